// Round 20
// baseline (110.041 us; speedup 1.0000x reference)
//
#include <hip/hip_runtime.h>
#include <hip/hip_bf16.h>

typedef unsigned short u16;
typedef unsigned int u32;
typedef __attribute__((ext_vector_type(8))) short bf16x8;   // 8 bf16 (MFMA x32 A/B frag)
typedef __attribute__((ext_vector_type(4))) float f32x4;    // MFMA C/D frag

#define BB 4
#define NN 2048
#define DD 256
#define HH 8
#define LAMBDA (-0.2550351f)  // -log2(e)/sqrt(32): folded into Q so sigmoid = rcp(1+exp2(s))

__device__ inline u16 bfu(float f) {
  __hip_bfloat16 h = __float2bfloat16(f);
  return *reinterpret_cast<u16*>(&h);
}
__device__ inline bf16x8 asfrag(uint4 v) { return __builtin_bit_cast(bf16x8, v); }

// ---------------- merged prep: x(permuted via LDS)+xb, mask->BITS, weights(LDS transpose) --
__global__ __launch_bounds__(256) void prep_kernel(
    const float* __restrict__ qdt, const float* __restrict__ boxes,
    const int* __restrict__ mask,
    const float* __restrict__ Wq, const float* __restrict__ Wk, const float* __restrict__ Wv,
    const float* __restrict__ Wo, const float* __restrict__ W1, const float* __restrict__ W2,
    const float* __restrict__ bq, const float* __restrict__ bk, const float* __restrict__ bv,
    float* __restrict__ xp, u16* __restrict__ xb, u32* __restrict__ m1,
    u16* __restrict__ wqkvT, u16* __restrict__ woT, u16* __restrict__ w1T, u16* __restrict__ w2T,
    float* __restrict__ bqkv) {
  __shared__ float xs[4160];              // x-perm staging (1024) / weight tile [64][65]
  const int bid = blockIdx.x, t = threadIdx.x;
  if (bid < 2048) {                       // x = qdt + boxes; xb linear bf16; xp permuted f32
    int i = bid * 256 + t;                // global float4 index; block = 4 rows
    float4 a = ((const float4*)qdt)[i];
    float4 b = ((const float4*)boxes)[i];
    float4 v = make_float4(a.x + b.x, a.y + b.y, a.z + b.z, a.w + b.w);
    ((ushort4*)xb)[i] = make_ushort4(bfu(v.x), bfu(v.y), bfu(v.z), bfu(v.w));
    ((float4*)xs)[t] = v;                 // xs[r*256 + 4*q + e], r=t>>6, q=t&63
    __syncthreads();
    // coalesced permuted write: xp[row][o]=x[row][16*(o&15)+(o>>4)], o=4q..4q+3
    const int r = t >> 6, q = t & 63;
    const float* xrow = xs + r * 256 + (q >> 2);      // + c
    float o0 = xrow[16 * (4 * (q & 3) + 0)];
    float o1 = xrow[16 * (4 * (q & 3) + 1)];
    float o2 = xrow[16 * (4 * (q & 3) + 2)];
    float o3 = xrow[16 * (4 * (q & 3) + 3)];
    ((float4*)(xp + (size_t)(bid * 4 + r) * 256))[q] = make_float4(o0, o1, o2, o3);
  } else if (bid < 2560) {                // mask: 32 ints -> 1 u32 of bits
    int i = (bid - 2048) * 256 + t;       // i in [0, 131072): m1[row][word]
    const int* src = mask + (size_t)i * 32;
    u32 bits = 0;
#pragma unroll
    for (int q4 = 0; q4 < 8; ++q4) {
      int4 m = *(const int4*)(src + q4 * 4);
      bits |= (m.x ? 1u : 0u) << (4 * q4);
      bits |= (m.y ? 1u : 0u) << (4 * q4 + 1);
      bits |= (m.z ? 1u : 0u) << (4 * q4 + 2);
      bits |= (m.w ? 1u : 0u) << (4 * q4 + 3);
    }
    m1[i] = bits;
  } else if (bid < 2656) {                // weight transpose via LDS: 96 blocks (6 mats x 16 tiles)
    const int b = bid - 2560;             // 0..95
    const int mtx = b >> 4, tile = b & 15;
    const int kt = (tile >> 2) * 64, nt = (tile & 3) * 64;
    const float* src = (mtx == 0) ? Wq : (mtx == 1) ? Wk : (mtx == 2) ? Wv
                     : (mtx == 3) ? Wo : (mtx == 4) ? W1 : W2;
    u16* dst = (mtx < 3) ? (wqkvT + mtx * 65536) : (mtx == 3) ? woT : (mtx == 4) ? w1T : w2T;
    const int r = t >> 2, q = t & 3;      // r: tile row 0..63, q: col quarter
#pragma unroll
    for (int j = 0; j < 4; ++j) {
      float4 v = *(const float4*)(src + (size_t)(kt + r) * 256 + nt + 16 * q + 4 * j);
      float* xr = xs + r * 65 + 16 * q + 4 * j;
      xr[0] = v.x; xr[1] = v.y; xr[2] = v.z; xr[3] = v.w;
    }
    __syncthreads();
    const int nn = r;
#pragma unroll
    for (int j = 0; j < 4; ++j) {
      ushort4 o;
      o.x = bfu(xs[(16 * q + 4 * j + 0) * 65 + nn]);
      o.y = bfu(xs[(16 * q + 4 * j + 1) * 65 + nn]);
      o.z = bfu(xs[(16 * q + 4 * j + 2) * 65 + nn]);
      o.w = bfu(xs[(16 * q + 4 * j + 3) * 65 + nn]);
      *(ushort4*)(dst + (size_t)(nt + nn) * 256 + kt + 16 * q + 4 * j) = o;
    }
  } else {                                // bias concat (1 block)
    if (t < 256) {
      bqkv[t] = bq[t];
      bqkv[256 + t] = bk[t];
      bqkv[512 + t] = bv[t];
    }
  }
}

// ---------------- fused QKV-side GEMM (XCD-swizzled): Q+K and V^T in one launch ----------
__global__ __launch_bounds__(256) void gemm_qkvt_kernel(
    const u16* __restrict__ xb, const u16* __restrict__ wqkvT,
    const float* __restrict__ bqkv,
    u16* __restrict__ qout, u16* __restrict__ kout, u16* __restrict__ vtout) {
  __shared__ u16 At[64][264];
  __shared__ u16 Bs[64][264];
  const int bid0 = blockIdx.x;
  const int bid = (bid0 & 7) * 192 + (bid0 >> 3);  // XCD swizzle (bijective, 1536=8*192):
                                                   // each XCD's qk-blocks share one B-panel
  const bool isqk = bid < 1024;
  const u16* A  = isqk ? xb : (wqkvT + 512 * 256);
  const u16* Bt = isqk ? wqkvT : xb;
  const int m0 = isqk ? (bid >> 3) * 64 : ((bid - 1024) >> 7) * 64;
  const int n0 = isqk ? (bid & 7) * 64 : ((bid - 1024) & 127) * 64;
  const int t = threadIdx.x;
  {
    const int row = t >> 2, cb = (t & 3) * 64;
    const u16* ga = A  + (size_t)(m0 + row) * 256 + cb;
    const u16* gb = Bt + (size_t)(n0 + row) * 256 + cb;
#pragma unroll
    for (int i = 0; i < 8; ++i) {
      *(int4*)&At[row][cb + i * 8] = *(const int4*)(ga + i * 8);
      *(int4*)&Bs[row][cb + i * 8] = *(const int4*)(gb + i * 8);
    }
  }
  __syncthreads();
  const int w = t >> 6, l = t & 63, g = l >> 4, c = l & 15;
  f32x4 acc[4] = {};
#pragma unroll
  for (int kk = 0; kk < 256; kk += 32) {
    bf16x8 af = *(const bf16x8*)&At[w * 16 + c][kk + g * 8];
#pragma unroll
    for (int j = 0; j < 4; ++j) {
      bf16x8 bfr = *(const bf16x8*)&Bs[j * 16 + c][kk + g * 8];
      acc[j] = __builtin_amdgcn_mfma_f32_16x16x32_bf16(af, bfr, acc[j], 0, 0, 0);
    }
  }
  if (isqk) {
    if (n0 < 256) {
#pragma unroll
      for (int j = 0; j < 4; ++j)
#pragma unroll
        for (int r = 0; r < 4; ++r) {
          int m = m0 + w * 16 + g * 4 + r, n = n0 + j * 16 + c;
          qout[(size_t)m * 256 + n] = bfu((acc[j][r] + bqkv[n]) * LAMBDA);
        }
    } else {
#pragma unroll
      for (int j = 0; j < 4; ++j)
#pragma unroll
        for (int r = 0; r < 4; ++r) {
          int m = m0 + w * 16 + g * 4 + r, n = n0 + j * 16 + c;
          int ch = n - 256;
          kout[(size_t)((m >> 11) * 8 + (ch >> 5)) * 65536 + (size_t)(m & 2047) * 32 + (ch & 31)]
              = bfu(acc[j][r] + bqkv[n]);
        }
    }
  } else {
#pragma unroll
    for (int j = 0; j < 4; ++j)
#pragma unroll
      for (int r = 0; r < 4; ++r) {
        int m = m0 + w * 16 + g * 4 + r;   // channel
        int n = n0 + j * 16 + c;           // token
        vtout[(size_t)m * 8192 + n] = bfu(acc[j][r] + bqkv[512 + m]);
      }
  }
}

// ---------------- fused sigmoid-gated attention (r18 PASSING build, unchanged) ----------
__global__ __launch_bounds__(256) void attn_kernel(
    const u16* __restrict__ qb,            // [8192][256] bf16, LAMBDA-scaled
    const u16* __restrict__ kb,            // [B][H][2048][32] bf16
    const u16* __restrict__ vtb,           // [256][8192] bf16 (V^T)
    const u32* __restrict__ m1,            // [2048][64] u32 mask bits
    u16* __restrict__ ob) {                // [8192][256] bf16
  __shared__ u32 Klds[2][64][20];          // 16 data u32 + 4 pad (row 80 B)
  __shared__ u32 Vlds[2][32][36];          // 32 data u32 + 4 pad (row 144 B)
  __shared__ u32 Plds[4][16][36];          // 32 data u32 + 4 pad, per-wave

  const int bid0 = blockIdx.x;
  const int bid = ((bid0 & 7) << 7) | (bid0 >> 3);   // XCD-locality remap (bijective)
  const int qt = bid & 31, h = (bid >> 5) & 7, b = bid >> 8;
  const int q0 = qt * 64;
  const int t = threadIdx.x, w = t >> 6, l = t & 63, g = l >> 4, c = l & 15;

  const bf16x8 qf = asfrag(*(const uint4*)(qb + (size_t)(b * NN + q0 + 16 * w + c) * 256 + h * 32 + 8 * g));
  f32x4 oacc[2] = {};

  const int srowK = t >> 2, ssegK = t & 3;
  const int srowV = t >> 3, ssegV = t & 7;
  const u16* kg = kb + (size_t)(b * 8 + h) * 65536 + srowK * 32 + ssegK * 8;
  const u16* vg = vtb + (size_t)(h * 32 + srowV) * 8192 + (size_t)b * NN + ssegV * 8;
  const u32* mr = m1 + (size_t)(q0 + 16 * w + c) * 64;   // lane's q-row bit words

  uint4 krg = *(const uint4*)kg;
  uint4 vrg = *(const uint4*)vg;
  uint2 mc = *(const uint2*)mr;            // tile-0 64-bit mask for this q-row
  *(uint4*)&Klds[0][srowK][ssegK * 4] = krg;
  *(uint4*)&Vlds[0][srowV][ssegV * 4] = vrg;
  __syncthreads();

  const f32x4 zf = {0.f, 0.f, 0.f, 0.f};
  u32* Pw = &Plds[w][0][0];

  for (int it = 0; it < 32; ++it) {
    const int cur = it & 1;
    uint2 mn;
    if (it < 31) {                         // prefetch tile it+1 (K, V, mask bits)
      const int kt = (it + 1) * 64;
      krg = *(const uint4*)(kg + (size_t)kt * 32);
      vrg = *(const uint4*)(vg + kt);
      mn = *(const uint2*)(mr + (it + 1) * 2);
    }
    __builtin_amdgcn_s_setprio(1);         // T5: favor compute over staging waves
#pragma unroll
    for (int tt = 0; tt < 4; ++tt) {
      bf16x8 kf = asfrag(*(const uint4*)&Klds[cur][16 * tt + c][4 * g]);
      f32x4 s = __builtin_amdgcn_mfma_f32_16x16x32_bf16(kf, qf, zf, 0, 0, 0);
      const u32 wd = (tt < 2) ? mc.x : mc.y;   // word sel compile-time per tt
      const int off = 16 * (tt & 1) + 4 * g;   // bit offset of elem r=0
      float p0 = (float)((wd >> (off + 0)) & 1u) * __builtin_amdgcn_rcpf(1.f + __builtin_amdgcn_exp2f(s[0]));
      float p1 = (float)((wd >> (off + 1)) & 1u) * __builtin_amdgcn_rcpf(1.f + __builtin_amdgcn_exp2f(s[1]));
      float p2 = (float)((wd >> (off + 2)) & 1u) * __builtin_amdgcn_rcpf(1.f + __builtin_amdgcn_exp2f(s[2]));
      float p3 = (float)((wd >> (off + 3)) & 1u) * __builtin_amdgcn_rcpf(1.f + __builtin_amdgcn_exp2f(s[3]));
      u32 w0, w1;
      asm("v_cvt_pk_bf16_f32 %0, %1, %2" : "=v"(w0) : "v"(p0), "v"(p1));
      asm("v_cvt_pk_bf16_f32 %0, %1, %2" : "=v"(w1) : "v"(p2), "v"(p3));
      *(uint2*)&Pw[c * 36 + 8 * tt + 2 * g] = make_uint2(w0, w1);
    }
    __builtin_amdgcn_s_setprio(0);
    // RULE-18 hard fence on wave-private P
    asm volatile("s_waitcnt lgkmcnt(0)" ::: "memory");
    __builtin_amdgcn_sched_barrier(0);
    __builtin_amdgcn_s_setprio(1);
#pragma unroll
    for (int kk = 0; kk < 2; ++kk) {
      bf16x8 pf = asfrag(*(const uint4*)&Pw[c * 36 + 16 * kk + 4 * g]);
#pragma unroll
      for (int d0 = 0; d0 < 2; ++d0) {
        bf16x8 vf = asfrag(*(const uint4*)&Vlds[cur][16 * d0 + c][16 * kk + 4 * g]);
        oacc[d0] = __builtin_amdgcn_mfma_f32_16x16x32_bf16(pf, vf, oacc[d0], 0, 0, 0);
      }
    }
    __builtin_amdgcn_s_setprio(0);
    if (it < 31) {
      *(uint4*)&Klds[cur ^ 1][srowK][ssegK * 4] = krg;
      *(uint4*)&Vlds[cur ^ 1][srowV][ssegV * 4] = vrg;
      mc = mn;
    }
    __syncthreads();
  }

  const size_t obase = (size_t)(b * NN + q0 + 16 * w) * 256 + h * 32;
#pragma unroll
  for (int d0 = 0; d0 < 2; ++d0)
#pragma unroll
    for (int r = 0; r < 4; ++r)
      ob[obase + (size_t)(4 * g + r) * 256 + 16 * d0 + c] = bfu(oacc[d0][r]);
}

// ---------------- fused tail v4: 512 blocks x 16 rows, 4-wave n-split, t1 in regs --------
// r9 geometry (2 blocks/CU, 8 waves/CU) + r12 register-residual dataflow.
__global__ __launch_bounds__(256) void tail_kernel(
    const u16* __restrict__ obuf, const u16* __restrict__ woT,
    const u16* __restrict__ w1T, const u16* __restrict__ w2T,
    const float* __restrict__ xp,          // [8192][256] f32, permuted [row][c*16+4w+j]
    const float* __restrict__ bo, const float* __restrict__ b1, const float* __restrict__ b2,
    const float* __restrict__ g1, const float* __restrict__ be1,
    const float* __restrict__ g2, const float* __restrict__ be2,
    float* __restrict__ out) {
  __shared__ u16 A[16][264];               // bf16 activation tile
  __shared__ float PS1[16][4], PS2[16][4]; // cross-wave LN partials
  const int t = threadIdx.x, w = t >> 6, l = t & 63, g = l >> 4, c = l & 15;
  const int m0 = blockIdx.x * 16;          // block's 16 rows
  const int n0 = w * 64;                   // wave's 64 cols
  const f32x4 zf4 = {0.f, 0.f, 0.f, 0.f};

  // ---- stage obuf rows m0..m0+15 (256 threads, 2 x 16B each) ----
  {
    const int srow = t >> 4, sseg = t & 15;
#pragma unroll
    for (int i = 0; i < 2; ++i) {
      uint4 v = *(const uint4*)(obuf + (size_t)(m0 + srow) * 256 + (sseg + 16 * i) * 8);
      *(uint4*)&A[srow][(sseg + 16 * i) * 8] = v;
    }
  }
  __syncthreads();

  f32x4 acc[4], t1[4];
  float mean[4], inv[4];

  // ---- GEMM1: obuf @ Wo (wave's 64 cols) ----
#pragma unroll
  for (int j = 0; j < 4; ++j) acc[j] = zf4;
#pragma unroll
  for (int kk = 0; kk < 256; kk += 32) {
    bf16x8 af = *(const bf16x8*)&A[c][kk + 8 * g];
#pragma unroll
    for (int j = 0; j < 4; ++j) {
      bf16x8 bfr = asfrag(*(const uint4*)(woT + (size_t)(n0 + 16 * j + c) * 256 + kk + 8 * g));
      acc[j] = __builtin_amdgcn_mfma_f32_16x16x32_bf16(af, bfr, acc[j], 0, 0, 0);
    }
  }
  // ---- epilogue1: z = acc + bo + x -> t1 regs; LN1 partials -> PS ----
  {
    float bov[4];
#pragma unroll
    for (int j = 0; j < 4; ++j) bov[j] = bo[n0 + 16 * j + c];
#pragma unroll
    for (int r = 0; r < 4; ++r) {
      const int rl = 4 * g + r;
      float4 xq = ((const float4*)(xp + (size_t)(m0 + rl) * 256 + c * 16))[w];
      float xa[4] = {xq.x, xq.y, xq.z, xq.w};
      float a1 = 0.f, a2 = 0.f;
#pragma unroll
      for (int j = 0; j < 4; ++j) {
        float z = acc[j][r] + bov[j] + xa[j];
        t1[j][r] = z;
        a1 += z; a2 += z * z;
      }
#pragma unroll
      for (int off = 1; off < 16; off <<= 1) {
        a1 += __shfl_xor(a1, off);
        a2 += __shfl_xor(a2, off);
      }
      if (c == 0) { PS1[rl][w] = a1; PS2[rl][w] = a2; }
    }
  }
  __syncthreads();
#pragma unroll
  for (int r = 0; r < 4; ++r) {
    const int rl = 4 * g + r;
    float s1 = PS1[rl][0] + PS1[rl][1] + PS1[rl][2] + PS1[rl][3];
    float s2 = PS2[rl][0] + PS2[rl][1] + PS2[rl][2] + PS2[rl][3];
    mean[r] = s1 * (1.f / 256.f);
    inv[r] = rsqrtf(s2 * (1.f / 256.f) - mean[r] * mean[r] + 1e-5f);
  }
  // normalize into t1 regs (kept for FF2 residual) + bf16 tile -> A
#pragma unroll
  for (int j = 0; j < 4; ++j) {
    const int n = n0 + 16 * j + c;
    const float gv = g1[n], bev = be1[n];
#pragma unroll
    for (int r = 0; r < 4; ++r) {
      float v = (t1[j][r] - mean[r]) * inv[r] * gv + bev;
      t1[j][r] = v;
      A[4 * g + r][n] = bfu(v);
    }
  }
  __syncthreads();

  // ---- GEMM2: t1 @ W1, relu ----
#pragma unroll
  for (int j = 0; j < 4; ++j) acc[j] = zf4;
#pragma unroll
  for (int kk = 0; kk < 256; kk += 32) {
    bf16x8 af = *(const bf16x8*)&A[c][kk + 8 * g];
#pragma unroll
    for (int j = 0; j < 4; ++j) {
      bf16x8 bfr = asfrag(*(const uint4*)(w1T + (size_t)(n0 + 16 * j + c) * 256 + kk + 8 * g));
      acc[j] = __builtin_amdgcn_mfma_f32_16x16x32_bf16(af, bfr, acc[j], 0, 0, 0);
    }
  }
  __syncthreads();                         // all waves done reading A
#pragma unroll
  for (int j = 0; j < 4; ++j) {
    const int n = n0 + 16 * j + c;
    const float bv = b1[n];
#pragma unroll
    for (int r = 0; r < 4; ++r) {
      float v = acc[j][r] + bv;
      A[4 * g + r][n] = bfu(v > 0.f ? v : 0.f);
    }
  }
  __syncthreads();

  // ---- GEMM3: h @ W2 ----
#pragma unroll
  for (int j = 0; j < 4; ++j) acc[j] = zf4;
#pragma unroll
  for (int kk = 0; kk < 256; kk += 32) {
    bf16x8 af = *(const bf16x8*)&A[c][kk + 8 * g];
#pragma unroll
    for (int j = 0; j < 4; ++j) {
      bf16x8 bfr = asfrag(*(const uint4*)(w2T + (size_t)(n0 + 16 * j + c) * 256 + kk + 8 * g));
      acc[j] = __builtin_amdgcn_mfma_f32_16x16x32_bf16(af, bfr, acc[j], 0, 0, 0);
    }
  }
  // ---- epilogue3: z = acc + b2 + t1 (regs); LN2 -> out ----
  {
    float b2v[4];
#pragma unroll
    for (int j = 0; j < 4; ++j) b2v[j] = b2[n0 + 16 * j + c];
#pragma unroll
    for (int r = 0; r < 4; ++r) {
      const int rl = 4 * g + r;
      float a1 = 0.f, a2 = 0.f;
#pragma unroll
      for (int j = 0; j < 4; ++j) {
        float z = acc[j][r] + b2v[j] + t1[j][r];
        t1[j][r] = z;
        a1 += z; a2 += z * z;
      }
#pragma unroll
      for (int off = 1; off < 16; off <<= 1) {
        a1 += __shfl_xor(a1, off);
        a2 += __shfl_xor(a2, off);
      }
      if (c == 0) { PS1[rl][w] = a1; PS2[rl][w] = a2; }
    }
  }
  __syncthreads();
#pragma unroll
  for (int r = 0; r < 4; ++r) {
    const int rl = 4 * g + r;
    float s1 = PS1[rl][0] + PS1[rl][1] + PS1[rl][2] + PS1[rl][3];
    float s2 = PS2[rl][0] + PS2[rl][1] + PS2[rl][2] + PS2[rl][3];
    mean[r] = s1 * (1.f / 256.f);
    inv[r] = rsqrtf(s2 * (1.f / 256.f) - mean[r] * mean[r] + 1e-5f);
  }
#pragma unroll
  for (int j = 0; j < 4; ++j) {
    const int n = n0 + 16 * j + c;
    const float gv = g2[n], bev = be2[n];
#pragma unroll
    for (int r = 0; r < 4; ++r)
      out[(size_t)(m0 + 4 * g + r) * 256 + n] = (t1[j][r] - mean[r]) * inv[r] * gv + bev;
  }
}

extern "C" void kernel_launch(void* const* d_in, const int* in_sizes, int n_in,
                              void* d_out, int out_size, void* d_ws, size_t ws_size,
                              hipStream_t stream) {
  const float* qdt   = (const float*)d_in[0];
  const float* boxes = (const float*)d_in[1];
  const int*   mask  = (const int*)d_in[2];
  const float* Wq = (const float*)d_in[3];
  const float* bq = (const float*)d_in[4];
  const float* Wk = (const float*)d_in[5];
  const float* bk = (const float*)d_in[6];
  const float* Wv = (const float*)d_in[7];
  const float* bv = (const float*)d_in[8];
  const float* Wo = (const float*)d_in[9];
  const float* bo = (const float*)d_in[10];
  const float* W1 = (const float*)d_in[11];
  const float* b1 = (const float*)d_in[12];
  const float* W2 = (const float*)d_in[13];
  const float* b2 = (const float*)d_in[14];
  const float* g1  = (const float*)d_in[15];
  const float* be1 = (const float*)d_in[16];
  const float* g2  = (const float*)d_in[17];
  const float* be2 = (const float*)d_in[18];

  char* ws = (char*)d_ws;
  float* xp    = (float*)(ws + 0);          // [8192,256] f32 permuted residual
  u16*   xb    = (u16*)  (ws + 8388608);
  u16*   qbuf  = (u16*)  (ws + 12582912);   // q, LAMBDA-scaled
  u16*   kbuf  = (u16*)  (ws + 16777216);   // [B][H][2048][32]
  u16*   vtbuf = (u16*)  (ws + 20971520);   // [256][8192]
  u16*   obuf  = (u16*)  (ws + 25165824);
  u16*   wqkvT = (u16*)  (ws + 46137344);   // [768,256]
  u16*   woT   = (u16*)  (ws + 46530560);
  u16*   w1T   = (u16*)  (ws + 46661632);
  u16*   w2T   = (u16*)  (ws + 46792704);
  float* bqkv  = (float*)(ws + 46923776);
  u32*   m1    = (u32*)  (ws + 46926848);   // [2048][64] u32 mask bits (512 KB)

  // merged prep: xp/xb (2048) + mask-bits (512) + weight-tiles (96) + bias (1)
  prep_kernel<<<2657, 256, 0, stream>>>(qdt, boxes, mask, Wq, Wk, Wv, Wo, W1, W2,
                                        bq, bk, bv, xp, xb, m1,
                                        wqkvT, woT, w1T, w2T, bqkv);
  // fused Q(scaled)/K(relayout) + V^T: 1536 blocks, XCD-swizzled
  gemm_qkvt_kernel<<<1536, 256, 0, stream>>>(xb, wqkvT, bqkv, qbuf, kbuf, vtbuf);
  // attention: 1024 blocks x (b,h,64q), XCD-swizzled
  attn_kernel<<<1024, 256, 0, stream>>>(qbuf, kbuf, vtbuf, m1, obuf);
  // fused tail v4: 512 blocks x 16 rows
  tail_kernel<<<512, 256, 0, stream>>>(obuf, woT, w1T, w2T, xp,
                                       bo, b1, b2, g1, be1, g2, be2, (float*)d_out);
}

// Round 21
// 109.537 us; speedup vs baseline: 1.0046x; 1.0046x over previous
//
#include <hip/hip_runtime.h>
#include <hip/hip_bf16.h>

typedef unsigned short u16;
typedef unsigned int u32;
typedef __attribute__((ext_vector_type(8))) short bf16x8;   // 8 bf16 (MFMA x32 A/B frag)
typedef __attribute__((ext_vector_type(4))) float f32x4;    // MFMA C/D frag

#define BB 4
#define NN 2048
#define DD 256
#define HH 8
#define LAMBDA (-0.2550351f)  // -log2(e)/sqrt(32): folded into Q so sigmoid = rcp(1+exp2(s))

__device__ inline u16 bfu(float f) {
  __hip_bfloat16 h = __float2bfloat16(f);
  return *reinterpret_cast<u16*>(&h);
}
__device__ inline bf16x8 asfrag(uint4 v) { return __builtin_bit_cast(bf16x8, v); }

// ---------------- merged prep: x(permuted via LDS)+xb, mask->BITS, weights(LDS transpose) --
__global__ __launch_bounds__(256) void prep_kernel(
    const float* __restrict__ qdt, const float* __restrict__ boxes,
    const int* __restrict__ mask,
    const float* __restrict__ Wq, const float* __restrict__ Wk, const float* __restrict__ Wv,
    const float* __restrict__ Wo, const float* __restrict__ W1, const float* __restrict__ W2,
    const float* __restrict__ bq, const float* __restrict__ bk, const float* __restrict__ bv,
    float* __restrict__ xp, u16* __restrict__ xb, u32* __restrict__ m1,
    u16* __restrict__ wqkvT, u16* __restrict__ woT, u16* __restrict__ w1T, u16* __restrict__ w2T,
    float* __restrict__ bqkv) {
  __shared__ float xs[4160];              // x-perm staging (1024) / weight tile [64][65]
  const int bid = blockIdx.x, t = threadIdx.x;
  if (bid < 2048) {                       // x = qdt + boxes; xb linear bf16; xp permuted f32
    int i = bid * 256 + t;                // global float4 index; block = 4 rows
    float4 a = ((const float4*)qdt)[i];
    float4 b = ((const float4*)boxes)[i];
    float4 v = make_float4(a.x + b.x, a.y + b.y, a.z + b.z, a.w + b.w);
    ((ushort4*)xb)[i] = make_ushort4(bfu(v.x), bfu(v.y), bfu(v.z), bfu(v.w));
    ((float4*)xs)[t] = v;                 // xs[r*256 + 4*q + e], r=t>>6, q=t&63
    __syncthreads();
    // coalesced permuted write: xp[row][o]=x[row][16*(o&15)+(o>>4)], o=4q..4q+3
    const int r = t >> 6, q = t & 63;
    const float* xrow = xs + r * 256 + (q >> 2);      // + c
    float o0 = xrow[16 * (4 * (q & 3) + 0)];
    float o1 = xrow[16 * (4 * (q & 3) + 1)];
    float o2 = xrow[16 * (4 * (q & 3) + 2)];
    float o3 = xrow[16 * (4 * (q & 3) + 3)];
    ((float4*)(xp + (size_t)(bid * 4 + r) * 256))[q] = make_float4(o0, o1, o2, o3);
  } else if (bid < 2560) {                // mask: 32 ints -> 1 u32 of bits
    int i = (bid - 2048) * 256 + t;       // i in [0, 131072): m1[row][word]
    const int* src = mask + (size_t)i * 32;
    u32 bits = 0;
#pragma unroll
    for (int q4 = 0; q4 < 8; ++q4) {
      int4 m = *(const int4*)(src + q4 * 4);
      bits |= (m.x ? 1u : 0u) << (4 * q4);
      bits |= (m.y ? 1u : 0u) << (4 * q4 + 1);
      bits |= (m.z ? 1u : 0u) << (4 * q4 + 2);
      bits |= (m.w ? 1u : 0u) << (4 * q4 + 3);
    }
    m1[i] = bits;
  } else if (bid < 2656) {                // weight transpose via LDS: 96 blocks (6 mats x 16 tiles)
    const int b = bid - 2560;             // 0..95
    const int mtx = b >> 4, tile = b & 15;
    const int kt = (tile >> 2) * 64, nt = (tile & 3) * 64;
    const float* src = (mtx == 0) ? Wq : (mtx == 1) ? Wk : (mtx == 2) ? Wv
                     : (mtx == 3) ? Wo : (mtx == 4) ? W1 : W2;
    u16* dst = (mtx < 3) ? (wqkvT + mtx * 65536) : (mtx == 3) ? woT : (mtx == 4) ? w1T : w2T;
    const int r = t >> 2, q = t & 3;      // r: tile row 0..63, q: col quarter
#pragma unroll
    for (int j = 0; j < 4; ++j) {
      float4 v = *(const float4*)(src + (size_t)(kt + r) * 256 + nt + 16 * q + 4 * j);
      float* xr = xs + r * 65 + 16 * q + 4 * j;
      xr[0] = v.x; xr[1] = v.y; xr[2] = v.z; xr[3] = v.w;
    }
    __syncthreads();
    const int nn = r;
#pragma unroll
    for (int j = 0; j < 4; ++j) {
      ushort4 o;
      o.x = bfu(xs[(16 * q + 4 * j + 0) * 65 + nn]);
      o.y = bfu(xs[(16 * q + 4 * j + 1) * 65 + nn]);
      o.z = bfu(xs[(16 * q + 4 * j + 2) * 65 + nn]);
      o.w = bfu(xs[(16 * q + 4 * j + 3) * 65 + nn]);
      *(ushort4*)(dst + (size_t)(nt + nn) * 256 + kt + 16 * q + 4 * j) = o;
    }
  } else {                                // bias concat (1 block)
    if (t < 256) {
      bqkv[t] = bq[t];
      bqkv[256 + t] = bk[t];
      bqkv[512 + t] = bv[t];
    }
  }
}

// ---------------- fused QKV-side GEMM: Q(scaled)+K(relayout) and V^T in one launch -------
__global__ __launch_bounds__(256) void gemm_qkvt_kernel(
    const u16* __restrict__ xb, const u16* __restrict__ wqkvT,
    const float* __restrict__ bqkv,
    u16* __restrict__ qout, u16* __restrict__ kout, u16* __restrict__ vtout) {
  __shared__ u16 At[64][264];
  __shared__ u16 Bs[64][264];
  const int bid = blockIdx.x;
  const bool isqk = bid < 1024;
  const u16* A  = isqk ? xb : (wqkvT + 512 * 256);
  const u16* Bt = isqk ? wqkvT : xb;
  const int m0 = isqk ? (bid >> 3) * 64 : ((bid - 1024) >> 7) * 64;
  const int n0 = isqk ? (bid & 7) * 64 : ((bid - 1024) & 127) * 64;
  const int t = threadIdx.x;
  {
    const int row = t >> 2, cb = (t & 3) * 64;
    const u16* ga = A  + (size_t)(m0 + row) * 256 + cb;
    const u16* gb = Bt + (size_t)(n0 + row) * 256 + cb;
#pragma unroll
    for (int i = 0; i < 8; ++i) {
      *(int4*)&At[row][cb + i * 8] = *(const int4*)(ga + i * 8);
      *(int4*)&Bs[row][cb + i * 8] = *(const int4*)(gb + i * 8);
    }
  }
  __syncthreads();
  const int w = t >> 6, l = t & 63, g = l >> 4, c = l & 15;
  f32x4 acc[4] = {};
#pragma unroll
  for (int kk = 0; kk < 256; kk += 32) {
    bf16x8 af = *(const bf16x8*)&At[w * 16 + c][kk + g * 8];
#pragma unroll
    for (int j = 0; j < 4; ++j) {
      bf16x8 bfr = *(const bf16x8*)&Bs[j * 16 + c][kk + g * 8];
      acc[j] = __builtin_amdgcn_mfma_f32_16x16x32_bf16(af, bfr, acc[j], 0, 0, 0);
    }
  }
  if (isqk) {
    if (n0 < 256) {
#pragma unroll
      for (int j = 0; j < 4; ++j)
#pragma unroll
        for (int r = 0; r < 4; ++r) {
          int m = m0 + w * 16 + g * 4 + r, n = n0 + j * 16 + c;
          qout[(size_t)m * 256 + n] = bfu((acc[j][r] + bqkv[n]) * LAMBDA);
        }
    } else {
#pragma unroll
      for (int j = 0; j < 4; ++j)
#pragma unroll
        for (int r = 0; r < 4; ++r) {
          int m = m0 + w * 16 + g * 4 + r, n = n0 + j * 16 + c;
          int ch = n - 256;
          kout[(size_t)((m >> 11) * 8 + (ch >> 5)) * 65536 + (size_t)(m & 2047) * 32 + (ch & 31)]
              = bfu(acc[j][r] + bqkv[n]);
        }
    }
  } else {
#pragma unroll
    for (int j = 0; j < 4; ++j)
#pragma unroll
      for (int r = 0; r < 4; ++r) {
        int m = m0 + w * 16 + g * 4 + r;   // channel
        int n = n0 + j * 16 + c;           // token
        vtout[(size_t)m * 8192 + n] = bfu(acc[j][r] + bqkv[512 + m]);
      }
  }
}

// ---------------- fused sigmoid-gated attention (r18 PASSING build, unchanged) ----------
__global__ __launch_bounds__(256) void attn_kernel(
    const u16* __restrict__ qb,            // [8192][256] bf16, LAMBDA-scaled
    const u16* __restrict__ kb,            // [B][H][2048][32] bf16
    const u16* __restrict__ vtb,           // [256][8192] bf16 (V^T)
    const u32* __restrict__ m1,            // [2048][64] u32 mask bits
    u16* __restrict__ ob) {                // [8192][256] bf16
  __shared__ u32 Klds[2][64][20];          // 16 data u32 + 4 pad (row 80 B)
  __shared__ u32 Vlds[2][32][36];          // 32 data u32 + 4 pad (row 144 B)
  __shared__ u32 Plds[4][16][36];          // 32 data u32 + 4 pad, per-wave

  const int bid0 = blockIdx.x;
  const int bid = ((bid0 & 7) << 7) | (bid0 >> 3);   // XCD-locality remap (bijective)
  const int qt = bid & 31, h = (bid >> 5) & 7, b = bid >> 8;
  const int q0 = qt * 64;
  const int t = threadIdx.x, w = t >> 6, l = t & 63, g = l >> 4, c = l & 15;

  const bf16x8 qf = asfrag(*(const uint4*)(qb + (size_t)(b * NN + q0 + 16 * w + c) * 256 + h * 32 + 8 * g));
  f32x4 oacc[2] = {};

  const int srowK = t >> 2, ssegK = t & 3;
  const int srowV = t >> 3, ssegV = t & 7;
  const u16* kg = kb + (size_t)(b * 8 + h) * 65536 + srowK * 32 + ssegK * 8;
  const u16* vg = vtb + (size_t)(h * 32 + srowV) * 8192 + (size_t)b * NN + ssegV * 8;
  const u32* mr = m1 + (size_t)(q0 + 16 * w + c) * 64;   // lane's q-row bit words

  uint4 krg = *(const uint4*)kg;
  uint4 vrg = *(const uint4*)vg;
  uint2 mc = *(const uint2*)mr;            // tile-0 64-bit mask for this q-row
  *(uint4*)&Klds[0][srowK][ssegK * 4] = krg;
  *(uint4*)&Vlds[0][srowV][ssegV * 4] = vrg;
  __syncthreads();

  const f32x4 zf = {0.f, 0.f, 0.f, 0.f};
  u32* Pw = &Plds[w][0][0];

  for (int it = 0; it < 32; ++it) {
    const int cur = it & 1;
    uint2 mn;
    if (it < 31) {                         // prefetch tile it+1 (K, V, mask bits)
      const int kt = (it + 1) * 64;
      krg = *(const uint4*)(kg + (size_t)kt * 32);
      vrg = *(const uint4*)(vg + kt);
      mn = *(const uint2*)(mr + (it + 1) * 2);
    }
    __builtin_amdgcn_s_setprio(1);         // T5: favor compute over staging waves
#pragma unroll
    for (int tt = 0; tt < 4; ++tt) {
      bf16x8 kf = asfrag(*(const uint4*)&Klds[cur][16 * tt + c][4 * g]);
      f32x4 s = __builtin_amdgcn_mfma_f32_16x16x32_bf16(kf, qf, zf, 0, 0, 0);
      const u32 wd = (tt < 2) ? mc.x : mc.y;   // word sel compile-time per tt
      const int off = 16 * (tt & 1) + 4 * g;   // bit offset of elem r=0
      float p0 = (float)((wd >> (off + 0)) & 1u) * __builtin_amdgcn_rcpf(1.f + __builtin_amdgcn_exp2f(s[0]));
      float p1 = (float)((wd >> (off + 1)) & 1u) * __builtin_amdgcn_rcpf(1.f + __builtin_amdgcn_exp2f(s[1]));
      float p2 = (float)((wd >> (off + 2)) & 1u) * __builtin_amdgcn_rcpf(1.f + __builtin_amdgcn_exp2f(s[2]));
      float p3 = (float)((wd >> (off + 3)) & 1u) * __builtin_amdgcn_rcpf(1.f + __builtin_amdgcn_exp2f(s[3]));
      u32 w0, w1;
      asm("v_cvt_pk_bf16_f32 %0, %1, %2" : "=v"(w0) : "v"(p0), "v"(p1));
      asm("v_cvt_pk_bf16_f32 %0, %1, %2" : "=v"(w1) : "v"(p2), "v"(p3));
      *(uint2*)&Pw[c * 36 + 8 * tt + 2 * g] = make_uint2(w0, w1);
    }
    __builtin_amdgcn_s_setprio(0);
    // RULE-18 hard fence on wave-private P
    asm volatile("s_waitcnt lgkmcnt(0)" ::: "memory");
    __builtin_amdgcn_sched_barrier(0);
    __builtin_amdgcn_s_setprio(1);
#pragma unroll
    for (int kk = 0; kk < 2; ++kk) {
      bf16x8 pf = asfrag(*(const uint4*)&Pw[c * 36 + 16 * kk + 4 * g]);
#pragma unroll
      for (int d0 = 0; d0 < 2; ++d0) {
        bf16x8 vf = asfrag(*(const uint4*)&Vlds[cur][16 * d0 + c][16 * kk + 4 * g]);
        oacc[d0] = __builtin_amdgcn_mfma_f32_16x16x32_bf16(pf, vf, oacc[d0], 0, 0, 0);
      }
    }
    __builtin_amdgcn_s_setprio(0);
    if (it < 31) {
      *(uint4*)&Klds[cur ^ 1][srowK][ssegK * 4] = krg;
      *(uint4*)&Vlds[cur ^ 1][srowV][ssegV * 4] = vrg;
      mc = mn;
    }
    __syncthreads();
  }

  const size_t obase = (size_t)(b * NN + q0 + 16 * w) * 256 + h * 32;
#pragma unroll
  for (int d0 = 0; d0 < 2; ++d0)
#pragma unroll
    for (int r = 0; r < 4; ++r)
      ob[obase + (size_t)(4 * g + r) * 256 + 16 * d0 + c] = bfu(oacc[d0][r]);
}

// ---------------- fused tail v3: Wo+res -> LN1 -> FF1+relu -> FF2+res -> LN2 -------------
// (r18 PASSING build: 256 blocks x 32 rows, 4-wave n-split, t1 in regs)
__global__ __launch_bounds__(256) void tail_kernel(
    const u16* __restrict__ obuf, const u16* __restrict__ woT,
    const u16* __restrict__ w1T, const u16* __restrict__ w2T,
    const float* __restrict__ xp,          // [8192][256] f32, permuted [row][c*16+4w+j]
    const float* __restrict__ bo, const float* __restrict__ b1, const float* __restrict__ b2,
    const float* __restrict__ g1, const float* __restrict__ be1,
    const float* __restrict__ g2, const float* __restrict__ be2,
    float* __restrict__ out) {
  __shared__ u16 A[32][264];               // bf16 activation tile
  __shared__ float PS1[32][4], PS2[32][4]; // cross-wave LN partials
  const int t = threadIdx.x, w = t >> 6, l = t & 63, g = l >> 4, c = l & 15;
  const int m0 = blockIdx.x * 32;          // block's 32 rows
  const int n0 = w * 64;                   // wave's 64 cols
  const f32x4 zf4 = {0.f, 0.f, 0.f, 0.f};

  // ---- stage obuf rows m0..m0+31 (256 threads, 4 x 16B each) ----
  {
    const int srow = t >> 3, sseg = t & 7;
#pragma unroll
    for (int i = 0; i < 4; ++i) {
      uint4 v = *(const uint4*)(obuf + (size_t)(m0 + srow) * 256 + (sseg + 8 * i) * 8);
      *(uint4*)&A[srow][(sseg + 8 * i) * 8] = v;
    }
  }
  __syncthreads();

  f32x4 acc[2][4], t1[2][4];
  float mean[2][4], inv[2][4];

  // ---- GEMM1: obuf @ Wo ----
#pragma unroll
  for (int rg = 0; rg < 2; ++rg)
#pragma unroll
    for (int j = 0; j < 4; ++j) acc[rg][j] = zf4;
#pragma unroll
  for (int kk = 0; kk < 256; kk += 32) {
    bf16x8 af0 = *(const bf16x8*)&A[c][kk + 8 * g];
    bf16x8 af1 = *(const bf16x8*)&A[16 + c][kk + 8 * g];
#pragma unroll
    for (int j = 0; j < 4; ++j) {
      bf16x8 bfr = asfrag(*(const uint4*)(woT + (size_t)(n0 + 16 * j + c) * 256 + kk + 8 * g));
      acc[0][j] = __builtin_amdgcn_mfma_f32_16x16x32_bf16(af0, bfr, acc[0][j], 0, 0, 0);
      acc[1][j] = __builtin_amdgcn_mfma_f32_16x16x32_bf16(af1, bfr, acc[1][j], 0, 0, 0);
    }
  }
  // ---- epilogue1: z = acc + bo + x -> t1 regs; LN1 partials -> PS ----
  {
    float bov[4];
#pragma unroll
    for (int j = 0; j < 4; ++j) bov[j] = bo[n0 + 16 * j + c];
#pragma unroll
    for (int rg = 0; rg < 2; ++rg)
#pragma unroll
      for (int r = 0; r < 4; ++r) {
        const int rl = 16 * rg + 4 * g + r;
        float4 xq = ((const float4*)(xp + (size_t)(m0 + rl) * 256 + c * 16))[w];
        float xa[4] = {xq.x, xq.y, xq.z, xq.w};
        float a1 = 0.f, a2 = 0.f;
#pragma unroll
        for (int j = 0; j < 4; ++j) {
          float z = acc[rg][j][r] + bov[j] + xa[j];
          t1[rg][j][r] = z;
          a1 += z; a2 += z * z;
        }
#pragma unroll
        for (int off = 1; off < 16; off <<= 1) {
          a1 += __shfl_xor(a1, off);
          a2 += __shfl_xor(a2, off);
        }
        if (c == 0) { PS1[rl][w] = a1; PS2[rl][w] = a2; }
      }
  }
  __syncthreads();
#pragma unroll
  for (int rg = 0; rg < 2; ++rg)
#pragma unroll
    for (int r = 0; r < 4; ++r) {
      const int rl = 16 * rg + 4 * g + r;
      float s1 = PS1[rl][0] + PS1[rl][1] + PS1[rl][2] + PS1[rl][3];
      float s2 = PS2[rl][0] + PS2[rl][1] + PS2[rl][2] + PS2[rl][3];
      mean[rg][r] = s1 * (1.f / 256.f);
      inv[rg][r] = rsqrtf(s2 * (1.f / 256.f) - mean[rg][r] * mean[rg][r] + 1e-5f);
    }
  // normalize into t1 regs (kept for FF2 residual) + bf16 tile -> A
#pragma unroll
  for (int j = 0; j < 4; ++j) {
    const int n = n0 + 16 * j + c;
    const float gv = g1[n], bev = be1[n];
#pragma unroll
    for (int rg = 0; rg < 2; ++rg)
#pragma unroll
      for (int r = 0; r < 4; ++r) {
        float v = (t1[rg][j][r] - mean[rg][r]) * inv[rg][r] * gv + bev;
        t1[rg][j][r] = v;
        A[16 * rg + 4 * g + r][n] = bfu(v);
      }
  }
  __syncthreads();

  // ---- GEMM2: t1 @ W1, relu ----
#pragma unroll
  for (int rg = 0; rg < 2; ++rg)
#pragma unroll
    for (int j = 0; j < 4; ++j) acc[rg][j] = zf4;
#pragma unroll
  for (int kk = 0; kk < 256; kk += 32) {
    bf16x8 af0 = *(const bf16x8*)&A[c][kk + 8 * g];
    bf16x8 af1 = *(const bf16x8*)&A[16 + c][kk + 8 * g];
#pragma unroll
    for (int j = 0; j < 4; ++j) {
      bf16x8 bfr = asfrag(*(const uint4*)(w1T + (size_t)(n0 + 16 * j + c) * 256 + kk + 8 * g));
      acc[0][j] = __builtin_amdgcn_mfma_f32_16x16x32_bf16(af0, bfr, acc[0][j], 0, 0, 0);
      acc[1][j] = __builtin_amdgcn_mfma_f32_16x16x32_bf16(af1, bfr, acc[1][j], 0, 0, 0);
    }
  }
  __syncthreads();                         // all waves done reading A
#pragma unroll
  for (int j = 0; j < 4; ++j) {
    const int n = n0 + 16 * j + c;
    const float bv = b1[n];
#pragma unroll
    for (int rg = 0; rg < 2; ++rg)
#pragma unroll
      for (int r = 0; r < 4; ++r) {
        float v = acc[rg][j][r] + bv;
        A[16 * rg + 4 * g + r][n] = bfu(v > 0.f ? v : 0.f);
      }
  }
  __syncthreads();

  // ---- GEMM3: h @ W2 ----
#pragma unroll
  for (int rg = 0; rg < 2; ++rg)
#pragma unroll
    for (int j = 0; j < 4; ++j) acc[rg][j] = zf4;
#pragma unroll
  for (int kk = 0; kk < 256; kk += 32) {
    bf16x8 af0 = *(const bf16x8*)&A[c][kk + 8 * g];
    bf16x8 af1 = *(const bf16x8*)&A[16 + c][kk + 8 * g];
#pragma unroll
    for (int j = 0; j < 4; ++j) {
      bf16x8 bfr = asfrag(*(const uint4*)(w2T + (size_t)(n0 + 16 * j + c) * 256 + kk + 8 * g));
      acc[0][j] = __builtin_amdgcn_mfma_f32_16x16x32_bf16(af0, bfr, acc[0][j], 0, 0, 0);
      acc[1][j] = __builtin_amdgcn_mfma_f32_16x16x32_bf16(af1, bfr, acc[1][j], 0, 0, 0);
    }
  }
  // ---- epilogue3: z = acc + b2 + t1 (regs); LN2 -> out ----
  {
    float b2v[4];
#pragma unroll
    for (int j = 0; j < 4; ++j) b2v[j] = b2[n0 + 16 * j + c];
#pragma unroll
    for (int rg = 0; rg < 2; ++rg)
#pragma unroll
      for (int r = 0; r < 4; ++r) {
        const int rl = 16 * rg + 4 * g + r;
        float a1 = 0.f, a2 = 0.f;
#pragma unroll
        for (int j = 0; j < 4; ++j) {
          float z = acc[rg][j][r] + b2v[j] + t1[rg][j][r];
          t1[rg][j][r] = z;
          a1 += z; a2 += z * z;
        }
#pragma unroll
        for (int off = 1; off < 16; off <<= 1) {
          a1 += __shfl_xor(a1, off);
          a2 += __shfl_xor(a2, off);
        }
        if (c == 0) { PS1[rl][w] = a1; PS2[rl][w] = a2; }
      }
  }
  __syncthreads();
#pragma unroll
  for (int rg = 0; rg < 2; ++rg)
#pragma unroll
    for (int r = 0; r < 4; ++r) {
      const int rl = 16 * rg + 4 * g + r;
      float s1 = PS1[rl][0] + PS1[rl][1] + PS1[rl][2] + PS1[rl][3];
      float s2 = PS2[rl][0] + PS2[rl][1] + PS2[rl][2] + PS2[rl][3];
      mean[rg][r] = s1 * (1.f / 256.f);
      inv[rg][r] = rsqrtf(s2 * (1.f / 256.f) - mean[rg][r] * mean[rg][r] + 1e-5f);
    }
#pragma unroll
  for (int j = 0; j < 4; ++j) {
    const int n = n0 + 16 * j + c;
    const float gv = g2[n], bev = be2[n];
#pragma unroll
    for (int rg = 0; rg < 2; ++rg)
#pragma unroll
      for (int r = 0; r < 4; ++r)
        out[(size_t)(m0 + 16 * rg + 4 * g + r) * 256 + n]
            = (t1[rg][j][r] - mean[rg][r]) * inv[rg][r] * gv + bev;
  }
}

extern "C" void kernel_launch(void* const* d_in, const int* in_sizes, int n_in,
                              void* d_out, int out_size, void* d_ws, size_t ws_size,
                              hipStream_t stream) {
  const float* qdt   = (const float*)d_in[0];
  const float* boxes = (const float*)d_in[1];
  const int*   mask  = (const int*)d_in[2];
  const float* Wq = (const float*)d_in[3];
  const float* bq = (const float*)d_in[4];
  const float* Wk = (const float*)d_in[5];
  const float* bk = (const float*)d_in[6];
  const float* Wv = (const float*)d_in[7];
  const float* bv = (const float*)d_in[8];
  const float* Wo = (const float*)d_in[9];
  const float* bo = (const float*)d_in[10];
  const float* W1 = (const float*)d_in[11];
  const float* b1 = (const float*)d_in[12];
  const float* W2 = (const float*)d_in[13];
  const float* b2 = (const float*)d_in[14];
  const float* g1  = (const float*)d_in[15];
  const float* be1 = (const float*)d_in[16];
  const float* g2  = (const float*)d_in[17];
  const float* be2 = (const float*)d_in[18];

  char* ws = (char*)d_ws;
  float* xp    = (float*)(ws + 0);          // [8192,256] f32 permuted residual
  u16*   xb    = (u16*)  (ws + 8388608);
  u16*   qbuf  = (u16*)  (ws + 12582912);   // q, LAMBDA-scaled
  u16*   kbuf  = (u16*)  (ws + 16777216);   // [B][H][2048][32]
  u16*   vtbuf = (u16*)  (ws + 20971520);   // [256][8192]
  u16*   obuf  = (u16*)  (ws + 25165824);
  u16*   wqkvT = (u16*)  (ws + 46137344);   // [768,256]
  u16*   woT   = (u16*)  (ws + 46530560);
  u16*   w1T   = (u16*)  (ws + 46661632);
  u16*   w2T   = (u16*)  (ws + 46792704);
  float* bqkv  = (float*)(ws + 46923776);
  u32*   m1    = (u32*)  (ws + 46926848);   // [2048][64] u32 mask bits (512 KB)

  // merged prep: xp/xb (2048) + mask-bits (512) + weight-tiles (96) + bias (1)
  prep_kernel<<<2657, 256, 0, stream>>>(qdt, boxes, mask, Wq, Wk, Wv, Wo, W1, W2,
                                        bq, bk, bv, xp, xb, m1,
                                        wqkvT, woT, w1T, w2T, bqkv);
  // fused Q(scaled)/K(relayout) + V^T: 1024 + 512 blocks
  gemm_qkvt_kernel<<<1536, 256, 0, stream>>>(xb, wqkvT, bqkv, qbuf, kbuf, vtbuf);
  // attention: 1024 blocks x (b,h,64q), XCD-swizzled
  attn_kernel<<<1024, 256, 0, stream>>>(qbuf, kbuf, vtbuf, m1, obuf);
  // fused tail: Wo+res -> LN1 -> FF1+relu -> FF2+res -> LN2 -> d_out
  tail_kernel<<<256, 256, 0, stream>>>(obuf, woT, w1T, w2T, xp,
                                       bo, b1, b2, g1, be1, g2, be2, (float*)d_out);
}